// Round 9
// baseline (144.980 us; speedup 1.0000x reference)
//
#include <hip/hip_runtime.h>
#include <math.h>

// KDE log-density: out[i] = log(1e-8 + (1/N) * sum_j exp(t1 - 50*||xe_i - xb_j||^2))
// N = 16384, D = 16, fp32 in/out.
//
// Round 9 = Round 5 core (69.3 us configuration) + NAMED-register 2-deep
// B prefetch pipeline.
//   R6 lesson: 64 live C-operand regs (G=4 per-row pe) -> scratch spill.
//   R7 lesson: wave-uniform pe bound kills screen selectivity (pe spans ~700).
//   R8 lesson: bfq[t % PF] ring -> compiler allocates the array in SCRATCH
//     (WRITE_SIZE 27 MB, FETCH 11 MB, main 43 us). Deep prefetch must be
//     expressed as named variables, never dynamically-indexed arrays.
//
// Numerics: inputs pre-scaled by sqrt(100*log2e) before bf16 cast, so one
// mfma_f32_32x32x16_bf16 with C = per-row pe yields d = 144.2695*dot + pe;
// tile screened out unless some d > THR - pb[col] (dropped terms < 2^-135
// shift the output < 1e-37; bf16 rounding safe: min pairwise sqdist >> 0.14).
// Rare hit path: atomicAdd into S, monotone atomicMin of log(1e-8+S_new/N)
// raw bits into out (all values negative => float-max == uint-min); kde_pre
// pre-writes out = log(1e-8), correct whenever S stays 0 (~every row).
// No LDS, no barriers, no device-scope fences (R4 lesson: serialized
// agent-scope acq/rel ticket cost ~150 us).

#define KDE_N 16384
#define KDE_D 16
#define MT 32                  // rows per wave m-tile
#define MWAVES 4               // waves per block
#define MB (MT * MWAVES)       // 128 eval rows per block
#define JSPLIT 16
#define JTILES (KDE_N / 32 / JSPLIT)   // 32 j-tiles per wave
#define THR (-135.0f)          // log2-domain underflow screen

typedef __attribute__((ext_vector_type(8)))  short   short8;
typedef __attribute__((ext_vector_type(16))) float   float16_t;

__device__ __forceinline__ unsigned short f32_to_bf16_rne(float f) {
    unsigned int u = __float_as_uint(f);
    unsigned int r = (u + 0x7FFFu + ((u >> 16) & 1u)) >> 16;
    return (unsigned short)r;
}

// ---- prologue: pe / (THR - pb), scaled bf16 casts, zero S, default out ----
__global__ void kde_pre(const float* __restrict__ xe, const float* __restrict__ xb,
                        float* __restrict__ S, float* __restrict__ pe,
                        float* __restrict__ pbthr, unsigned short* __restrict__ xe16,
                        unsigned short* __restrict__ xb16, float* __restrict__ out)
{
    const int t = blockIdx.x * blockDim.x + threadIdx.x;   // 0..32767
    const int row = t & (KDE_N - 1);
    const bool isB = t >= KDE_N;
    const float* src = (isB ? xb : xe) + (size_t)row * KDE_D;
    const float4* s4 = (const float4*)src;
    const float SQSC = 12.011224664550577f;   // sqrt(100*log2e)
    float q = 0.f;
    unsigned int w[8];
    #pragma unroll
    for (int k = 0; k < 4; ++k) {
        float4 v = s4[k];
        q += v.x*v.x + v.y*v.y + v.z*v.z + v.w*v.w;
        w[2*k+0] = (unsigned int)f32_to_bf16_rne(v.x * SQSC)
                 | ((unsigned int)f32_to_bf16_rne(v.y * SQSC) << 16);
        w[2*k+1] = (unsigned int)f32_to_bf16_rne(v.z * SQSC)
                 | ((unsigned int)f32_to_bf16_rne(v.w * SQSC) << 16);
    }
    unsigned short* dst = (isB ? xb16 : xe16) + (size_t)row * KDE_D;
    uint4* d4 = (uint4*)dst;
    d4[0] = make_uint4(w[0], w[1], w[2], w[3]);
    d4[1] = make_uint4(w[4], w[5], w[6], w[7]);
    const float T1L2E  = -17.8920067984f;       // log2e * t1
    const float C72    = 72.134752044447963f;   // 50 * log2e
    const float LOG1EM8 = -18.420680743952367f; // log(1e-8)
    if (!isB) { pe[row] = T1L2E - C72 * q; S[row] = 0.f; out[row] = LOG1EM8; }
    else      { pbthr[row] = THR + C72 * q; }   // THR - pb,  pb = -C72*b2
}

// ---- main: MFMA (C = per-row pe) + screen; named 2-deep prefetch ----
__global__ __launch_bounds__(256, 8) void kde_main(
    const unsigned short* __restrict__ xe16, const unsigned short* __restrict__ xb16,
    const float* __restrict__ pe, const float* __restrict__ pbthr,
    float* __restrict__ S, float* __restrict__ out)
{
    const int lane = threadIdx.x & 63;
    const int wave = threadIdx.x >> 6;
    const int m0   = blockIdx.x * MB + wave * MT;
    const int jt0  = blockIdx.y * JTILES;

    const int col  = lane & 31;   // A row / B col / C col
    const int half = lane >> 5;   // k-half for A/B frags; row-group for C

    // A fragment, loaded once (K=16 == D)
    const short8 af = *(const short8*)(xe16 + (size_t)(m0 + col) * KDE_D + half * 8);

    // C operand = exact per-row pe: row = (r&3)+8*(r>>2)+4*half
    float16_t perv;
    #pragma unroll
    for (int r = 0; r < 16; ++r)
        perv[r] = pe[m0 + (r & 3) + 8 * (r >> 2) + 4 * half];

    const float INVN = 1.0f / (float)KDE_N;

    auto screen = [&](const float16_t& d, float thrv) {
        float m1 = fmaxf(fmaxf(d[0],  d[1]),  d[2]);
        float m2 = fmaxf(fmaxf(d[3],  d[4]),  d[5]);
        float m3 = fmaxf(fmaxf(d[6],  d[7]),  d[8]);
        float m4 = fmaxf(fmaxf(d[9],  d[10]), d[11]);
        float m5 = fmaxf(fmaxf(d[12], d[13]), d[14]);
        float x  = fmaxf(fmaxf(m1, m2), m3);
        float y  = fmaxf(fmaxf(m4, m5), d[15]);
        float mx = fmaxf(x, y);
        if (__any(mx > thrv)) {
            // rare: some term may exceed 2^-135
            const float pbv = THR - thrv;   // = pb[col]
            #pragma unroll
            for (int r = 0; r < 16; ++r) {
                float e = exp2f(d[r] + pbv);
                if (e != 0.f) {
                    const int row = m0 + (r & 3) + 8 * (r >> 2) + 4 * half;
                    float old  = atomicAdd(&S[row], e);
                    float cand = logf(1e-8f + (old + e) * INVN);
                    // all cands negative: float-max == uint-min on raw bits
                    atomicMin((unsigned int*)&out[row], __float_as_uint(cand));
                }
            }
        }
    };

    const unsigned short* bbase = xb16 + (size_t)(jt0 * 32 + col) * KDE_D + half * 8;
    const float*          tbase = pbthr + (jt0 * 32 + col);

    auto ldb = [&](int t) -> short8 {
        return *(const short8*)(bbase + (size_t)t * 32 * KDE_D);
    };
    auto ldt = [&](int t) -> float { return tbase[(size_t)t * 32]; };

    // Named-register 2-wide pipeline, prefetch distance 2 tiles.
    short8 bf0 = ldb(0), bf1 = ldb(1);
    float  th0 = ldt(0), th1 = ldt(1);

    for (int t = 0; t < JTILES; t += 2) {
        // uniform clamped prefetch indices (branch-free; harmless reload at end)
        const int p0 = (t + 2 < JTILES) ? t + 2 : t;
        const int p1 = (t + 3 < JTILES) ? t + 3 : t + 1;
        short8 nf0 = ldb(p0); float nt0 = ldt(p0);
        short8 nf1 = ldb(p1); float nt1 = ldt(p1);

        float16_t d0 = __builtin_amdgcn_mfma_f32_32x32x16_bf16(af, bf0, perv, 0, 0, 0);
        screen(d0, th0);
        float16_t d1 = __builtin_amdgcn_mfma_f32_32x32x16_bf16(af, bf1, perv, 0, 0, 0);
        screen(d1, th1);

        bf0 = nf0; th0 = nt0; bf1 = nf1; th1 = nt1;
    }
}

extern "C" void kernel_launch(void* const* d_in, const int* in_sizes, int n_in,
                              void* d_out, int out_size, void* d_ws, size_t ws_size,
                              hipStream_t stream)
{
    const float* xe = (const float*)d_in[0];  // x_eval [16384,16] fp32
    const float* xb = (const float*)d_in[1];  // x_base [16384,16] fp32
    float* out = (float*)d_out;

    // ws layout: S[16384] | pe[16384] | pbthr[16384] | xe16 | xb16
    float* S     = (float*)d_ws;
    float* pe    = S + KDE_N;
    float* pbthr = pe + KDE_N;
    unsigned short* xe16 = (unsigned short*)(pbthr + KDE_N);
    unsigned short* xb16 = xe16 + (size_t)KDE_N * KDE_D;

    kde_pre<<<(2 * KDE_N) / 256, 256, 0, stream>>>(xe, xb, S, pe, pbthr, xe16, xb16, out);
    dim3 grid(KDE_N / MB, JSPLIT);   // (128, 16) = 2048 blocks
    kde_main<<<grid, MWAVES * 64, 0, stream>>>(xe16, xb16, pe, pbthr, S, out);
}

// Round 10
// 71.652 us; speedup vs baseline: 2.0234x; 2.0234x over previous
//
#include <hip/hip_runtime.h>
#include <math.h>

// KDE log-density: out[i] = log(1e-8 + (1/N) * sum_j exp(t1 - 50*||xe_i - xb_j||^2))
// N = 16384, D = 16, fp32 in/out.
//
// Round 10 = Round 9 pipeline under a 128-register budget.
//   R6/R8/R9 post-mortems converge on ONE mechanism: __launch_bounds__'s
//   waves/EU bound caps the unified VGPR+AGPR file (8/EU -> 64 regs/wave,
//   reported as 32 arch VGPRs + 32 AGPRs). R9's live set (~75+: A-frag 4,
//   pe C-operand 16, 2 B-frags + 2 prefetch 16, two in-flight MFMA C/D 32,
//   addressing) spilled to scratch under that cap (WRITE 35 MB -> 96 us).
//   Fix: __launch_bounds__(256, 4) -> 128 regs/wave. The 2-deep named
//   pipeline + dual independent MFMA/screen chains supply ILP in place of
//   the halved TLP.
//   R7 lesson stands: screen needs exact per-row pe (riding the C operand).
//
// Numerics: inputs pre-scaled by sqrt(100*log2e) before bf16 cast, so one
// mfma_f32_32x32x16_bf16 with C = per-row pe yields d = 144.2695*dot + pe;
// tile screened out unless some d > THR - pb[col] (dropped terms < 2^-135
// shift the output < 1e-37; bf16 rounding safe: min pairwise sqdist >> 0.14).
// Rare hit path: atomicAdd into S, monotone atomicMin of log(1e-8+S_new/N)
// raw bits into out (all negative => float-max == uint-min); kde_pre
// pre-writes out = log(1e-8), correct whenever S stays 0 (~every row).
// No LDS, no barriers, no device-scope fences (R4 lesson: serialized
// agent-scope acq/rel ticket cost ~150 us).

#define KDE_N 16384
#define KDE_D 16
#define MT 32                  // rows per wave m-tile
#define MWAVES 4               // waves per block
#define MB (MT * MWAVES)       // 128 eval rows per block
#define JSPLIT 16
#define JTILES (KDE_N / 32 / JSPLIT)   // 32 j-tiles per wave
#define THR (-135.0f)          // log2-domain underflow screen

typedef __attribute__((ext_vector_type(8)))  short   short8;
typedef __attribute__((ext_vector_type(16))) float   float16_t;

__device__ __forceinline__ unsigned short f32_to_bf16_rne(float f) {
    unsigned int u = __float_as_uint(f);
    unsigned int r = (u + 0x7FFFu + ((u >> 16) & 1u)) >> 16;
    return (unsigned short)r;
}

// ---- prologue: pe / (THR - pb), scaled bf16 casts, zero S, default out ----
__global__ void kde_pre(const float* __restrict__ xe, const float* __restrict__ xb,
                        float* __restrict__ S, float* __restrict__ pe,
                        float* __restrict__ pbthr, unsigned short* __restrict__ xe16,
                        unsigned short* __restrict__ xb16, float* __restrict__ out)
{
    const int t = blockIdx.x * blockDim.x + threadIdx.x;   // 0..32767
    const int row = t & (KDE_N - 1);
    const bool isB = t >= KDE_N;
    const float* src = (isB ? xb : xe) + (size_t)row * KDE_D;
    const float4* s4 = (const float4*)src;
    const float SQSC = 12.011224664550577f;   // sqrt(100*log2e)
    float q = 0.f;
    unsigned int w[8];
    #pragma unroll
    for (int k = 0; k < 4; ++k) {
        float4 v = s4[k];
        q += v.x*v.x + v.y*v.y + v.z*v.z + v.w*v.w;
        w[2*k+0] = (unsigned int)f32_to_bf16_rne(v.x * SQSC)
                 | ((unsigned int)f32_to_bf16_rne(v.y * SQSC) << 16);
        w[2*k+1] = (unsigned int)f32_to_bf16_rne(v.z * SQSC)
                 | ((unsigned int)f32_to_bf16_rne(v.w * SQSC) << 16);
    }
    unsigned short* dst = (isB ? xb16 : xe16) + (size_t)row * KDE_D;
    uint4* d4 = (uint4*)dst;
    d4[0] = make_uint4(w[0], w[1], w[2], w[3]);
    d4[1] = make_uint4(w[4], w[5], w[6], w[7]);
    const float T1L2E  = -17.8920067984f;       // log2e * t1
    const float C72    = 72.134752044447963f;   // 50 * log2e
    const float LOG1EM8 = -18.420680743952367f; // log(1e-8)
    if (!isB) { pe[row] = T1L2E - C72 * q; S[row] = 0.f; out[row] = LOG1EM8; }
    else      { pbthr[row] = THR + C72 * q; }   // THR - pb,  pb = -C72*b2
}

// ---- main: MFMA (C = per-row pe) + screen; named 2-deep prefetch ----
__global__ __launch_bounds__(256, 4) void kde_main(
    const unsigned short* __restrict__ xe16, const unsigned short* __restrict__ xb16,
    const float* __restrict__ pe, const float* __restrict__ pbthr,
    float* __restrict__ S, float* __restrict__ out)
{
    const int lane = threadIdx.x & 63;
    const int wave = threadIdx.x >> 6;
    const int m0   = blockIdx.x * MB + wave * MT;
    const int jt0  = blockIdx.y * JTILES;

    const int col  = lane & 31;   // A row / B col / C col
    const int half = lane >> 5;   // k-half for A/B frags; row-group for C

    // A fragment, loaded once (K=16 == D)
    const short8 af = *(const short8*)(xe16 + (size_t)(m0 + col) * KDE_D + half * 8);

    // C operand = exact per-row pe: row = (r&3)+8*(r>>2)+4*half
    float16_t perv;
    #pragma unroll
    for (int r = 0; r < 16; ++r)
        perv[r] = pe[m0 + (r & 3) + 8 * (r >> 2) + 4 * half];

    const float INVN = 1.0f / (float)KDE_N;

    auto screen = [&](const float16_t& d, float thrv) {
        float m1 = fmaxf(fmaxf(d[0],  d[1]),  d[2]);
        float m2 = fmaxf(fmaxf(d[3],  d[4]),  d[5]);
        float m3 = fmaxf(fmaxf(d[6],  d[7]),  d[8]);
        float m4 = fmaxf(fmaxf(d[9],  d[10]), d[11]);
        float m5 = fmaxf(fmaxf(d[12], d[13]), d[14]);
        float x  = fmaxf(fmaxf(m1, m2), m3);
        float y  = fmaxf(fmaxf(m4, m5), d[15]);
        float mx = fmaxf(x, y);
        if (__any(mx > thrv)) {
            // rare: some term may exceed 2^-135
            const float pbv = THR - thrv;   // = pb[col]
            #pragma unroll
            for (int r = 0; r < 16; ++r) {
                float e = exp2f(d[r] + pbv);
                if (e != 0.f) {
                    const int row = m0 + (r & 3) + 8 * (r >> 2) + 4 * half;
                    float old  = atomicAdd(&S[row], e);
                    float cand = logf(1e-8f + (old + e) * INVN);
                    // all cands negative: float-max == uint-min on raw bits
                    atomicMin((unsigned int*)&out[row], __float_as_uint(cand));
                }
            }
        }
    };

    const unsigned short* bbase = xb16 + (size_t)(jt0 * 32 + col) * KDE_D + half * 8;
    const float*          tbase = pbthr + (jt0 * 32 + col);

    auto ldb = [&](int t) -> short8 {
        return *(const short8*)(bbase + (size_t)t * 32 * KDE_D);
    };
    auto ldt = [&](int t) -> float { return tbase[(size_t)t * 32]; };

    // Named-register 2-wide pipeline, prefetch distance 2 tiles.
    short8 bf0 = ldb(0), bf1 = ldb(1);
    float  th0 = ldt(0), th1 = ldt(1);

    for (int t = 0; t < JTILES; t += 2) {
        // uniform clamped prefetch indices (branch-free; harmless reload at end)
        const int p0 = (t + 2 < JTILES) ? t + 2 : t;
        const int p1 = (t + 3 < JTILES) ? t + 3 : t + 1;
        short8 nf0 = ldb(p0); float nt0 = ldt(p0);
        short8 nf1 = ldb(p1); float nt1 = ldt(p1);

        float16_t d0 = __builtin_amdgcn_mfma_f32_32x32x16_bf16(af, bf0, perv, 0, 0, 0);
        screen(d0, th0);
        float16_t d1 = __builtin_amdgcn_mfma_f32_32x32x16_bf16(af, bf1, perv, 0, 0, 0);
        screen(d1, th1);

        bf0 = nf0; th0 = nt0; bf1 = nf1; th1 = nt1;
    }
}

extern "C" void kernel_launch(void* const* d_in, const int* in_sizes, int n_in,
                              void* d_out, int out_size, void* d_ws, size_t ws_size,
                              hipStream_t stream)
{
    const float* xe = (const float*)d_in[0];  // x_eval [16384,16] fp32
    const float* xb = (const float*)d_in[1];  // x_base [16384,16] fp32
    float* out = (float*)d_out;

    // ws layout: S[16384] | pe[16384] | pbthr[16384] | xe16 | xb16
    float* S     = (float*)d_ws;
    float* pe    = S + KDE_N;
    float* pbthr = pe + KDE_N;
    unsigned short* xe16 = (unsigned short*)(pbthr + KDE_N);
    unsigned short* xb16 = xe16 + (size_t)KDE_N * KDE_D;

    kde_pre<<<(2 * KDE_N) / 256, 256, 0, stream>>>(xe, xb, S, pe, pbthr, xe16, xb16, out);
    dim3 grid(KDE_N / MB, JSPLIT);   // (128, 16) = 2048 blocks
    kde_main<<<grid, MWAVES * 64, 0, stream>>>(xe16, xb16, pe, pbthr, S, out);
}